// Round 9
// baseline (439.049 us; speedup 1.0000x reference)
//
#include <hip/hip_runtime.h>
#include <hip/hip_bf16.h>

#define LL 80
#define NPIX 784
#define PBATCH 15680

#define DI __device__ __forceinline__

typedef short s8v __attribute__((ext_vector_type(8)));     // 8 bf16 = 16B
typedef short short4v __attribute__((ext_vector_type(4))); // 4 bf16 = 8B
typedef float f32x4 __attribute__((ext_vector_type(4)));   // MFMA acc

DI float b2f(__hip_bfloat16 x) { return __bfloat162float(x); }
DI float s2f(short h) { return __uint_as_float(((unsigned int)(unsigned short)h) << 16); }

// f32 -> bf16 bits, round-nearest-even
DI short f2b(float x) {
    unsigned int b = __float_as_uint(x);
    b += 0x7fffu + ((b >> 16) & 1u);
    return (short)(b >> 16);
}

// F=1: buffer holds f32; F=0: buffer holds bf16
template <int F> DI float LD(const void* p, int i) {
    if (F) return ((const float*)p)[i];
    return b2f(((const __hip_bfloat16*)p)[i]);
}
DI float LDf(int f, const void* p, int i) { return f ? ((const float*)p)[i] : b2f(((const __hip_bfloat16*)p)[i]); }

DI float fast_tanh(float x) {
    float e = __expf(2.0f * x);
    return 1.0f - 2.0f / (e + 1.0f);
}
DI float fast_sigmoid(float x) { return 1.0f / (1.0f + __expf(-x)); }

// ---------------- dtype probe (proven R3-R8) ----------------
__global__ __launch_bounds__(256) void detect_dtype(const void* probe, int n, int* flag) {
    __shared__ int bad;
    if (threadIdx.x == 0) bad = 0;
    __syncthreads();
    int c = 0;
    for (int i = threadIdx.x; i < n; i += 256) {
        float v = b2f(((const __hip_bfloat16*)probe)[i]);
        if (!(fabsf(v) < 1000.0f)) c++;
    }
    if (c) atomicAdd(&bad, c);
    __syncthreads();
    if (threadIdx.x == 0) *flag = (bad > 8) ? 1 : 0;   // 1 => inputs are f32
}

// ---------------- prep sub-parts ----------------
DI void cvt_part(int f, const void* src, short* __restrict__ dst, int blk, int n) {
    int i0 = (blk * 256 + threadIdx.x) * 4;
    if (i0 >= n) return;
    if (f) {
        float4 v = *(const float4*)((const float*)src + i0);
        short4v o = { f2b(v.x), f2b(v.y), f2b(v.z), f2b(v.w) };
        *(short4v*)(dst + i0) = o;
    } else {
        *(short4v*)(dst + i0) = *(const short4v*)((const short*)src + i0);
    }
}

// wcat[4096][1024]: rows 0-1023 w3 folded, 1024-2047 w4 folded, 2048-3071 w5 folded, 3072-4095 u3
DI void wcat_part(int f, const void* w3, const void* w4, const void* w5, const void* u3,
                  short* __restrict__ wcat, int blk) {
    int i0 = (blk * 256 + threadIdx.x) * 4;
    int nr = i0 >> 10, k = i0 & 1023;
    int j = nr >> 10, r = nr & 1023;
    const void* W = (j == 0) ? w3 : (j == 1) ? w4 : (j == 2) ? w5 : u3;
    float4 v;
    if (j < 3) {
        if (f) {
            float4 x = *(const float4*)((const float*)W + r * 2048 + k);
            float4 y = *(const float4*)((const float*)W + r * 2048 + 1024 + k);
            v.x = x.x + y.x; v.y = x.y + y.y; v.z = x.z + y.z; v.w = x.w + y.w;
        } else {
            const short* Ws = (const short*)W;
            short4v x = *(const short4v*)(Ws + r * 2048 + k);
            short4v y = *(const short4v*)(Ws + r * 2048 + 1024 + k);
            v.x = s2f(x.x) + s2f(y.x); v.y = s2f(x.y) + s2f(y.y);
            v.z = s2f(x.z) + s2f(y.z); v.w = s2f(x.w) + s2f(y.w);
        }
    } else {
        if (f) v = *(const float4*)((const float*)W + r * 1024 + k);
        else {
            short4v x = *(const short4v*)((const short*)W + r * 1024 + k);
            v.x = s2f(x.x); v.y = s2f(x.y); v.z = s2f(x.z); v.w = s2f(x.w);
        }
    }
    short4v o = { f2b(v.x), f2b(v.y), f2b(v.z), f2b(v.w) };
    *(short4v*)(wcat + i0) = o;
}

// u partial: uP[jsplit][k] = sum_{j in split} fca_w[j] * fc3_w[j,k]; float4 over k, coalesced rows
template <int F>
DI void u_part(const void* fc3_w, const void* fca_w, float* __restrict__ uP, int jsplit) {
    int k4 = threadIdx.x * 4;
    float4 acc = {0.f, 0.f, 0.f, 0.f};
    for (int j = jsplit * 64; j < jsplit * 64 + 64; j++) {
        float fa = LD<F>(fca_w, j);
        float4 row;
        if (F) row = *(const float4*)((const float*)fc3_w + j * 1024 + k4);
        else {
            short4v x = *(const short4v*)((const short*)fc3_w + j * 1024 + k4);
            row.x = s2f(x.x); row.y = s2f(x.y); row.z = s2f(x.z); row.w = s2f(x.w);
        }
        acc.x += fa * row.x; acc.y += fa * row.y;
        acc.z += fa * row.z; acc.w += fa * row.w;
    }
    *(float4*)(uP + jsplit * 1024 + k4) = acc;
}

template <int F>
DI void c0_part(const void* fc3_b, const void* fca_w, const void* fca_b,
                float* c0, float* red) {
    float acc = 0.f;
    for (int j = threadIdx.x; j < 1024; j += 256)
        acc += LD<F>(fc3_b, j) * LD<F>(fca_w, j);
    red[threadIdx.x] = acc;
    __syncthreads();
    for (int s = 128; s > 0; s >>= 1) {
        if (threadIdx.x < s) red[threadIdx.x] += red[threadIdx.x + s];
        __syncthreads();
    }
    if (threadIdx.x == 0) *c0 = red[0] + LD<F>(fca_b, 0);
}

// SIMT GEMM for tiny fc2 (M=80,N=1024,K=300), lds = 2176 floats
template <int F>
DI void fc2_part(float* lds, const void* word, const void* fc2_w, float* C, int bx, int by) {
    float* As = lds;            // [16][68]
    float* Ws2 = lds + 1088;    // [16][68]
    const int tid = threadIdx.x;
    const int tx = tid & 15, ty = tid >> 4;
    const int m0 = by * 64, n0 = bx * 64;
    const int M = 80, K = 300;
    float acc[4][4] = {};

    for (int k0 = 0; k0 < K; k0 += 16) {
#pragma unroll
        for (int i = 0; i < 4; i++) {
            int idx = tid + i * 256;
            int kk = idx & 15, mm = idx >> 4;
            int m = m0 + mm, k = k0 + kk;
            As[kk * 68 + mm] = (m < M && k < K) ? LD<F>(word, m * 300 + k) : 0.f;
        }
#pragma unroll
        for (int i = 0; i < 4; i++) {
            int idx = tid + i * 256;
            int kk = idx & 15, nn = idx >> 4;
            int n = n0 + nn, k = k0 + kk;
            Ws2[kk * 68 + nn] = (k < K) ? LD<F>(fc2_w, n * 300 + k) : 0.f;
        }
        __syncthreads();
#pragma unroll
        for (int kk = 0; kk < 16; kk++) {
            float4 av = *(const float4*)(&As[kk * 68 + ty * 4]);
            float4 wv = *(const float4*)(&Ws2[kk * 68 + tx * 4]);
            float a4[4] = {av.x, av.y, av.z, av.w};
            float w4[4] = {wv.x, wv.y, wv.z, wv.w};
#pragma unroll
            for (int i = 0; i < 4; i++)
#pragma unroll
                for (int j = 0; j < 4; j++)
                    acc[i][j] += a4[i] * w4[j];
        }
        __syncthreads();
    }

    for (int i = 0; i < 4; i++) {
        int m = m0 + ty * 4 + i;
        if (m >= M) continue;
        for (int j = 0; j < 4; j++)
            C[m * 1024 + n0 + tx * 4 + j] = acc[i][j];
    }
}

// ONE dispatch for all independent prep. Long-pole blocks FIRST (R8 lesson:
// prep_u/fc2 at the grid tail gated the whole 63 µs dispatch).
__global__ __launch_bounds__(256) void mega_prep(
    const int* flag,
    const void* fmap, const void* fc1_w, const void* u5w, const void* fco_w,
    const void* w3, const void* w4, const void* w5, const void* u3,
    const void* fc3_w, const void* fc3_b, const void* fca_w, const void* fca_b,
    const void* word, const void* fc2_w,
    short* fmap_b, short* fc1w_b, short* u5w_b, short* wcat_b, short* fcow_b,
    float* uP, float* c0, float* f_wd) {
    __shared__ float lds[2176];
    int f = *flag;
    int bid = blockIdx.x;
    if (bid < 16) {
        if (f) u_part<1>(fc3_w, fca_w, uP, bid);
        else   u_part<0>(fc3_w, fca_w, uP, bid);
    } else if (bid == 16) {
        if (f) c0_part<1>(fc3_b, fca_w, fca_b, c0, lds);
        else   c0_part<0>(fc3_b, fca_w, fca_b, c0, lds);
    } else if (bid < 49) {
        int r = bid - 17;
        if (f) fc2_part<1>(lds, word, fc2_w, f_wd, r & 15, r >> 4);
        else   fc2_part<0>(lds, word, fc2_w, f_wd, r & 15, r >> 4);
    }
    else if (bid < 833)  cvt_part(f, fmap,  fmap_b, bid - 49,   802816);
    else if (bid < 1857) cvt_part(f, fc1_w, fc1w_b, bid - 833,  1048576);
    else if (bid < 2881) cvt_part(f, u5w,   u5w_b,  bid - 1857, 1048576);
    else if (bid < 6977) wcat_part(f, w3, w4, w5, u3, wcat_b, bid - 2881);
    else                 cvt_part(f, fco_w, fcow_b, bid - 6977, 4194304);
}

// ================= bf16 MFMA GEMM core (proven R6/R8) =================
DI void mcore_b(const short* __restrict__ A, int lda,
                const short* __restrict__ B, int ldb,
                float* __restrict__ C, int ldc,
                int M, int kb, int ke, int m0, int n0) {
    __shared__ short As[4][64][8];
    __shared__ short Ws[4][64][8];
    const int tid = threadIdx.x;
    const int wv = tid >> 6, lane = tid & 63;
    const int mA = tid & 63, qA = tid >> 6;
    f32x4 acc[4] = {};

    for (int k0 = kb; k0 < ke; k0 += 32) {
        s8v va = {0,0,0,0,0,0,0,0};
        int gm = m0 + mA;
        if (gm < M) va = *(const s8v*)(A + gm * lda + k0 + 8 * qA);
        *(s8v*)&As[mA >> 4][(mA & 15) | (qA << 4)][0] = va;
        s8v vb = *(const s8v*)(B + (n0 + mA) * ldb + k0 + 8 * qA);
        *(s8v*)&Ws[mA >> 4][(mA & 15) | (qA << 4)][0] = vb;
        __syncthreads();
        s8v af = *(const s8v*)&As[wv][lane][0];
#pragma unroll
        for (int nf = 0; nf < 4; nf++) {
            s8v bf = *(const s8v*)&Ws[nf][lane][0];
            acc[nf] = __builtin_amdgcn_mfma_f32_16x16x32_bf16(af, bf, acc[nf], 0, 0, 0);
        }
        __syncthreads();
    }

    const int q = lane >> 4, cc = lane & 15;
#pragma unroll
    for (int nf = 0; nf < 4; nf++) {
        int n = n0 + 16 * nf + cc;
#pragma unroll
        for (int r = 0; r < 4; r++) {
            int m = m0 + 16 * wv + q * 4 + r;
            if (m < M) C[m * ldc + n] = acc[nf][r];
        }
    }
}

__global__ __launch_bounds__(256) void mfma_fc1(
    const short* __restrict__ fmap_b, const short* __restrict__ fc1w_b,
    float* __restrict__ fhP) {
    int z = blockIdx.z;
    mcore_b(fmap_b, 1024, fc1w_b, 1024, fhP + z * 802816, 1024,
            NPIX, z * 512, z * 512 + 512, blockIdx.y * 64, blockIdx.x * 64);
}

__global__ __launch_bounds__(256) void mfma_gate(
    const short* __restrict__ a_b, const short* __restrict__ nodes_b,
    const short* __restrict__ wcat_b, float* __restrict__ gP) {
    int z = blockIdx.z;
    const short* A = (blockIdx.x >= 48) ? nodes_b : a_b;
    mcore_b(A, 1024, wcat_b, 1024, gP + z * 1310720, 4096,
            320, z * 512, z * 512 + 512, blockIdx.y * 64, blockIdx.x * 64);
}

// u5 GEMM with FUSED ew_upd epilogue (no k-split; epilogue owns exactly the
// (m, c=n) elements it needs). Writes nodes f32 + nodes_b bf16 directly.
__global__ __launch_bounds__(256) void mfma_u5f(
    const int* flag, const short* __restrict__ rn_b, const short* __restrict__ u5w_b,
    const float* __restrict__ gP,
    const void* b3, const void* u3b, const void* b5, const void* u5b,
    float* __restrict__ nodes, short* __restrict__ nodes_b) {
    __shared__ short As[4][64][8];
    __shared__ short Ws[4][64][8];
    const int tid = threadIdx.x;
    const int wv = tid >> 6, lane = tid & 63;
    const int mA = tid & 63, qA = tid >> 6;
    const int m0 = blockIdx.y * 64, n0 = blockIdx.x * 64;
    f32x4 acc[4] = {};

    for (int k0 = 0; k0 < 1024; k0 += 32) {
        s8v va = *(const s8v*)(rn_b + (m0 + mA) * 1024 + k0 + 8 * qA);
        *(s8v*)&As[mA >> 4][(mA & 15) | (qA << 4)][0] = va;
        s8v vb = *(const s8v*)(u5w_b + (n0 + mA) * 1024 + k0 + 8 * qA);
        *(s8v*)&Ws[mA >> 4][(mA & 15) | (qA << 4)][0] = vb;
        __syncthreads();
        s8v af = *(const s8v*)&As[wv][lane][0];
#pragma unroll
        for (int nf = 0; nf < 4; nf++) {
            s8v bf = *(const s8v*)&Ws[nf][lane][0];
            acc[nf] = __builtin_amdgcn_mfma_f32_16x16x32_bf16(af, bf, acc[nf], 0, 0, 0);
        }
        __syncthreads();
    }

    const int f = *flag;
    const int q = lane >> 4, cc = lane & 15;
#pragma unroll
    for (int nf = 0; nf < 4; nf++) {
        int n = n0 + 16 * nf + cc;
        float bb3 = LDf(f, b3, n), bu3 = LDf(f, u3b, n);
        float bb5 = LDf(f, b5, n), bu5 = LDf(f, u5b, n);
#pragma unroll
        for (int r = 0; r < 4; r++) {
            int m = m0 + 16 * wv + q * 4 + r;
            int i = m * 1024 + n, base = m * 4096;
            float az = gP[base + n]        + gP[1310720 + base + n];
            float ah = gP[base + 2048 + n] + gP[1310720 + base + 2048 + n];
            float ux = gP[base + 3072 + n] + gP[1310720 + base + 3072 + n];
            float z = fast_sigmoid(az + ux + bb3 + bu3);
            float h = fast_tanh(ah + acc[nf][r] + bb5 + bu5);
            float nd = (1.f - z) * nodes[i] + z * h;
            nodes[i] = nd;
            nodes_b[i] = f2b(nd);
        }
    }
}

// final GEMM with FUSED bias+tanh+store epilogue (no k-split).
__global__ __launch_bounds__(256) void mfma_finf(
    const int* flag, const short* __restrict__ nodes_b, const short* __restrict__ g_b,
    const short* __restrict__ fcow_b, const void* fco_b, void* out) {
    __shared__ short As[4][64][8];
    __shared__ short Ws[4][64][8];
    const int tid = threadIdx.x;
    const int wv = tid >> 6, lane = tid & 63;
    const int mA = tid & 63, qA = tid >> 6;
    const int m0 = blockIdx.y * 64, n0 = blockIdx.x * 64;
    f32x4 acc[4] = {};

    for (int k0 = 0; k0 < 2048; k0 += 32) {
        const short* Ap = (k0 < 1024) ? nodes_b : (g_b - 1024);
        s8v va = *(const s8v*)(Ap + (m0 + mA) * 1024 + k0 + 8 * qA);
        *(s8v*)&As[mA >> 4][(mA & 15) | (qA << 4)][0] = va;
        s8v vb = *(const s8v*)(fcow_b + (n0 + mA) * 2048 + k0 + 8 * qA);
        *(s8v*)&Ws[mA >> 4][(mA & 15) | (qA << 4)][0] = vb;
        __syncthreads();
        s8v af = *(const s8v*)&As[wv][lane][0];
#pragma unroll
        for (int nf = 0; nf < 4; nf++) {
            s8v bf = *(const s8v*)&Ws[nf][lane][0];
            acc[nf] = __builtin_amdgcn_mfma_f32_16x16x32_bf16(af, bf, acc[nf], 0, 0, 0);
        }
        __syncthreads();
    }

    const int f = *flag;
    const int q = lane >> 4, cc = lane & 15;
#pragma unroll
    for (int nf = 0; nf < 4; nf++) {
        int n = n0 + 16 * nf + cc;
        float bias = LDf(f, fco_b, n);
#pragma unroll
        for (int r = 0; r < 4; r++) {
            int m = m0 + 16 * wv + q * 4 + r;
            float v = fast_tanh(acc[nf][r] + bias);
            if (f) ((float*)out)[m * 2048 + n] = v;
            else   ((__hip_bfloat16*)out)[m * 2048 + n] = __float2bfloat16(v);
        }
    }
}

// ---------------- coeff: float4, sums 16 u-partials ----------------
__global__ __launch_bounds__(256) void coeff_kernel(
    const float* __restrict__ fhP, const float* __restrict__ f_wd,
    const float* __restrict__ uP, const float* __restrict__ c0p,
    float* __restrict__ s) {
    int n = blockIdx.x;  // 0..783
    __shared__ float4 fh4[256];
    __shared__ float4 uu4[256];
    int t = threadIdx.x;
    {
        float4 a0 = *(const float4*)(fhP + n * 1024 + t * 4);
        float4 a1 = *(const float4*)(fhP + 802816 + n * 1024 + t * 4);
        float4 fv = {a0.x + a1.x, a0.y + a1.y, a0.z + a1.z, a0.w + a1.w};
        fh4[t] = fv;
        float4 uv = {0.f, 0.f, 0.f, 0.f};
        for (int p = 0; p < 16; p++) {
            float4 q4 = *(const float4*)(uP + p * 1024 + t * 4);
            uv.x += q4.x; uv.y += q4.y; uv.z += q4.z; uv.w += q4.w;
        }
        uu4[t] = uv;
    }
    __syncthreads();
    float c0 = *c0p;
    int wave = t >> 6, lane = t & 63;
    int b = n / 196, hw = n % 196;
    int l0 = blockIdx.y * 40;
    for (int l = l0 + wave; l < l0 + 40; l += 4) {
        const float4* fd4 = (const float4*)(f_wd + l * 1024);
        float p = 0.f;
#pragma unroll
        for (int k = 0; k < 4; k++) {
            int idx = lane + k * 64;
            float4 h = fh4[idx];
            float4 d = fd4[idx];
            float4 uu = uu4[idx];
            p += fast_tanh(h.x * d.x) * uu.x;
            p += fast_tanh(h.y * d.y) * uu.y;
            p += fast_tanh(h.z * d.z) * uu.z;
            p += fast_tanh(h.w * d.w) * uu.w;
        }
        for (int off = 32; off > 0; off >>= 1) p += __shfl_down(p, off);
        if (lane == 0) s[b * PBATCH + hw * LL + l] = p + c0;
    }
}

// ---------------- softmax over contiguous 196-chunks ----------------
__global__ __launch_bounds__(64) void softmax196(float* __restrict__ s) {
    float* p = s + blockIdx.x * 196;
    int lane = threadIdx.x;
    float v[4];
    float mx = -1e30f;
#pragma unroll
    for (int i = 0; i < 4; i++) {
        int idx = lane + i * 64;
        v[i] = (idx < 196) ? p[idx] : -1e30f;
        mx = fmaxf(mx, v[i]);
    }
    for (int off = 32; off > 0; off >>= 1) mx = fmaxf(mx, __shfl_down(mx, off));
    mx = __shfl(mx, 0);
    float sum = 0.f;
#pragma unroll
    for (int i = 0; i < 4; i++) {
        int idx = lane + i * 64;
        if (idx < 196) { v[i] = __expf(v[i] - mx); sum += v[i]; }
    }
    for (int off = 32; off > 0; off >>= 1) sum += __shfl_down(sum, off);
    sum = __shfl(sum, 0);
    float inv = 1.f / sum;
#pragma unroll
    for (int i = 0; i < 4; i++) {
        int idx = lane + i * 64;
        if (idx < 196) p[idx] = v[i] * inv;
    }
}

// ---------------- g: reads bf16 fmap_b, 4 c per thread ----------------
__global__ __launch_bounds__(256) void g_kernel(
    const float* __restrict__ s, const short* __restrict__ fmap_b,
    float* __restrict__ nodes, short* __restrict__ nodes_b, short* __restrict__ g_b) {
    int bl = blockIdx.x;
    int b = bl / LL, l = bl % LL;
    __shared__ float co[196];
    for (int i = threadIdx.x; i < 196; i += 256)
        co[i] = s[b * PBATCH + i * LL + l];
    __syncthreads();
    int c4 = threadIdx.x * 4;
    const short* base = fmap_b + b * 196 * 1024 + c4;
    float a0 = 0.f, a1 = 0.f, a2 = 0.f, a3 = 0.f;
    for (int hw = 0; hw < 196; hw++) {
        short4v v = *(const short4v*)(base + hw * 1024);
        float w = co[hw];
        a0 += w * s2f(v.x); a1 += w * s2f(v.y);
        a2 += w * s2f(v.z); a3 += w * s2f(v.w);
    }
    int o = bl * 1024 + c4;
    float4 fa = {a0, a1, a2, a3};
    *(float4*)(nodes + o) = fa;
    short4v bb = { f2b(a0), f2b(a1), f2b(a2), f2b(a3) };
    *(short4v*)(nodes_b + o) = bb;
    *(short4v*)(g_b + o) = bb;
}

// ---------------- adj: 4 c per thread ----------------
template <int F>
DI void adj_core(float* arw, const void* adj, const float* nodes, short* a_b) {
    int bl = blockIdx.x;
    int b = bl / LL, l = bl % LL;
    if (threadIdx.x < LL) arw[threadIdx.x] = LD<F>(adj, l * LL + threadIdx.x);
    __syncthreads();
    int c4 = threadIdx.x * 4;
    const float* nb = nodes + b * LL * 1024 + c4;
    float a0 = 0.f, a1 = 0.f, a2 = 0.f, a3 = 0.f;
    for (int m = 0; m < LL; m++) {
        float am = arw[m];
        float4 nd = *(const float4*)(nb + m * 1024);
        a0 += am * nd.x; a1 += am * nd.y; a2 += am * nd.z; a3 += am * nd.w;
    }
    short4v bb = { f2b(a0), f2b(a1), f2b(a2), f2b(a3) };
    *(short4v*)(a_b + bl * 1024 + c4) = bb;
}

__global__ __launch_bounds__(256) void adj_kernel(
    const int* flag, const void* adj, const float* nodes, short* a_b) {
    __shared__ float arw[LL];
    if (*flag) adj_core<1>(arw, adj, nodes, a_b);
    else       adj_core<0>(arw, adj, nodes, a_b);
}

// ---------------- rn_b = bf16( sigmoid(ar + u3x + b4 + u3b) * nodes ), x4 ----------------
template <int F>
DI void ew_r_core(const float* gP, const float* nodes,
                  const void* b4, const void* u3b, short* rn_b, int i4) {
    int m = i4 >> 10, c = i4 & 1023;
    int base = m * 4096;
    float4 r0 = *(const float4*)(gP + base + 1024 + c);
    float4 r1 = *(const float4*)(gP + 1310720 + base + 1024 + c);
    float4 x0 = *(const float4*)(gP + base + 3072 + c);
    float4 x1 = *(const float4*)(gP + 1310720 + base + 3072 + c);
    float4 nd = *(const float4*)(nodes + i4);
    short4v o;
    o.x = f2b(fast_sigmoid(r0.x + r1.x + x0.x + x1.x + LD<F>(b4, c)   + LD<F>(u3b, c))   * nd.x);
    o.y = f2b(fast_sigmoid(r0.y + r1.y + x0.y + x1.y + LD<F>(b4, c+1) + LD<F>(u3b, c+1)) * nd.y);
    o.z = f2b(fast_sigmoid(r0.z + r1.z + x0.z + x1.z + LD<F>(b4, c+2) + LD<F>(u3b, c+2)) * nd.z);
    o.w = f2b(fast_sigmoid(r0.w + r1.w + x0.w + x1.w + LD<F>(b4, c+3) + LD<F>(u3b, c+3)) * nd.w);
    *(short4v*)(rn_b + i4) = o;
}

__global__ void ew_r(const int* flag, const float* gP, const float* nodes,
                     const void* b4, const void* u3b, short* rn_b, int n) {
    int i4 = (blockIdx.x * 256 + threadIdx.x) * 4;
    if (i4 >= n) return;
    if (*flag) ew_r_core<1>(gP, nodes, b4, u3b, rn_b, i4);
    else       ew_r_core<0>(gP, nodes, b4, u3b, rn_b, i4);
}

extern "C" void kernel_launch(void* const* d_in, const int* in_sizes, int n_in,
                              void* d_out, int out_size, void* d_ws, size_t ws_size,
                              hipStream_t stream) {
    const void* fmap  = d_in[0];
    const void* word  = d_in[1];
    const void* adjm  = d_in[2];
    const void* fc1_w = d_in[3];
    const void* fc2_w = d_in[4];
    const void* fc3_w = d_in[5];
    const void* fc3_b = d_in[6];
    const void* fca_w = d_in[7];
    const void* fca_b = d_in[8];
    const void* w3    = d_in[9];
    const void* b3    = d_in[10];
    const void* u3    = d_in[11];
    const void* u3b   = d_in[12];
    const void* w4    = d_in[13];
    const void* b4    = d_in[14];
    const void* w5    = d_in[15];
    const void* b5    = d_in[16];
    const void* u5    = d_in[17];
    const void* u5b   = d_in[18];
    const void* fco_w = d_in[19];
    const void* fco_b = d_in[20];

    // ---- workspace: increments in FLOATS (bf16 buffers = elems/2). 33.6 MB.
    int*   flag    = (int*)d_ws;
    float* P       = (float*)d_ws + 16;
    float* nodes   = P;                       P += 327680;   // f32, persistent
    short* nodes_b = (short*)P;               P += 163840;   // 327680 bf16
    short* g_b     = (short*)P;               P += 163840;   // 327680 bf16
    short* a_b     = (short*)P;               P += 163840;   // 327680 bf16
    short* rn_b    = (short*)P;               P += 163840;   // 327680 bf16
    short* u5w_b   = (short*)P;               P += 524288;   // 1048576 bf16
    short* wcat_b  = (short*)P;               P += 2097152;  // 4194304 bf16
    float* R       = P;                                      // overlay region
    // semantic phase (2,692,368 f)
    float* fhP    = R;                            // 2 x 802816
    float* f_wd   = R + 1605632;                  // 81920
    float* uP     = f_wd + 81920;                 // 16 x 1024 partials
    float* c0     = uP + 16384;                   // 16
    float* s      = c0 + 16;                      // 62720
    short* fmap_b = (short*)(s + 62720);          // 802816 shorts = 401408 f
    short* fc1w_b = (short*)(s + 62720 + 401408); // 1048576 shorts = 524288 f
    // fco weight copy: past semantic tail, disjoint from gP (GGNN)
    short* fcow_b = (short*)(R + 2692368);        // 4194304 shorts = 2097152 f
    // GGNN phase (overlays semantic only): gP 2 x 1310720 = R..R+2621440
    float* gP     = R;

    // ---- dtype detection ----
    detect_dtype<<<1, 256, 0, stream>>>(fc1_w, 4096, flag);

    // ---- all independent prep in ONE dispatch (incl. fco cvt) ----
    mega_prep<<<11073, 256, 0, stream>>>(flag, fmap, fc1_w, u5, fco_w,
                                         w3, w4, w5, u3,
                                         fc3_w, fc3_b, fca_w, fca_b,
                                         word, fc2_w,
                                         fmap_b, fc1w_b, u5w_b, wcat_b, fcow_b,
                                         uP, c0, f_wd);

    // ---- semantic stage ----
    mfma_fc1<<<dim3(16, 13, 2), 256, 0, stream>>>(fmap_b, fc1w_b, fhP);
    coeff_kernel<<<dim3(NPIX, 2), 256, 0, stream>>>(fhP, f_wd, uP, c0, s);
    softmax196<<<320, 64, 0, stream>>>(s);
    g_kernel<<<320, 256, 0, stream>>>(s, fmap_b, nodes, nodes_b, g_b);

    // ---- GGNN: 3 time steps (u5 GEMM has fused ew_upd epilogue) ----
    for (int t = 0; t < 3; t++) {
        adj_kernel<<<320, 256, 0, stream>>>(flag, adjm, nodes, a_b);
        mfma_gate<<<dim3(64, 5, 2), 256, 0, stream>>>(a_b, nodes_b, wcat_b, gP);
        ew_r<<<320, 256, 0, stream>>>(flag, gP, nodes, b4, u3b, rn_b, 327680);
        mfma_u5f<<<dim3(16, 5), 256, 0, stream>>>(flag, rn_b, u5w_b, gP,
                                                  b3, u3b, b5, u5b, nodes, nodes_b);
    }

    // ---- output: tanh([nodes|g] @ fco_w.T + fco_b), fused epilogue ----
    mfma_finf<<<dim3(32, 5), 256, 0, stream>>>(flag, nodes_b, g_b, fcow_b, fco_b, d_out);
}

// Round 10
// 394.458 us; speedup vs baseline: 1.1130x; 1.1130x over previous
//
#include <hip/hip_runtime.h>
#include <hip/hip_bf16.h>

#define LL 80
#define NPIX 784
#define PBATCH 15680

#define DI __device__ __forceinline__

typedef short s8v __attribute__((ext_vector_type(8)));     // 8 bf16 = 16B
typedef short short4v __attribute__((ext_vector_type(4))); // 4 bf16 = 8B
typedef float f32x4 __attribute__((ext_vector_type(4)));   // MFMA acc

DI float b2f(__hip_bfloat16 x) { return __bfloat162float(x); }
DI float s2f(short h) { return __uint_as_float(((unsigned int)(unsigned short)h) << 16); }

// f32 -> bf16 bits, round-nearest-even
DI short f2b(float x) {
    unsigned int b = __float_as_uint(x);
    b += 0x7fffu + ((b >> 16) & 1u);
    return (short)(b >> 16);
}

// F=1: buffer holds f32; F=0: buffer holds bf16
template <int F> DI float LD(const void* p, int i) {
    if (F) return ((const float*)p)[i];
    return b2f(((const __hip_bfloat16*)p)[i]);
}
DI float LDf(int f, const void* p, int i) { return f ? ((const float*)p)[i] : b2f(((const __hip_bfloat16*)p)[i]); }

DI float fast_tanh(float x) {
    float e = __expf(2.0f * x);
    return 1.0f - 2.0f / (e + 1.0f);
}
DI float fast_sigmoid(float x) { return 1.0f / (1.0f + __expf(-x)); }

// ---------------- dtype probe (proven R3-R9) ----------------
__global__ __launch_bounds__(256) void detect_dtype(const void* probe, int n, int* flag) {
    __shared__ int bad;
    if (threadIdx.x == 0) bad = 0;
    __syncthreads();
    int c = 0;
    for (int i = threadIdx.x; i < n; i += 256) {
        float v = b2f(((const __hip_bfloat16*)probe)[i]);
        if (!(fabsf(v) < 1000.0f)) c++;
    }
    if (c) atomicAdd(&bad, c);
    __syncthreads();
    if (threadIdx.x == 0) *flag = (bad > 8) ? 1 : 0;   // 1 => inputs are f32
}

// ---------------- prep sub-parts ----------------
DI void cvt_part(int f, const void* src, short* __restrict__ dst, int blk, int n) {
    int i0 = (blk * 256 + threadIdx.x) * 4;
    if (i0 >= n) return;
    if (f) {
        float4 v = *(const float4*)((const float*)src + i0);
        short4v o = { f2b(v.x), f2b(v.y), f2b(v.z), f2b(v.w) };
        *(short4v*)(dst + i0) = o;
    } else {
        *(short4v*)(dst + i0) = *(const short4v*)((const short*)src + i0);
    }
}

// wcat[4096][1024]: rows 0-1023 w3 folded, 1024-2047 w4 folded, 2048-3071 w5 folded, 3072-4095 u3
DI void wcat_part(int f, const void* w3, const void* w4, const void* w5, const void* u3,
                  short* __restrict__ wcat, int blk) {
    int i0 = (blk * 256 + threadIdx.x) * 4;
    int nr = i0 >> 10, k = i0 & 1023;
    int j = nr >> 10, r = nr & 1023;
    const void* W = (j == 0) ? w3 : (j == 1) ? w4 : (j == 2) ? w5 : u3;
    float4 v;
    if (j < 3) {
        if (f) {
            float4 x = *(const float4*)((const float*)W + r * 2048 + k);
            float4 y = *(const float4*)((const float*)W + r * 2048 + 1024 + k);
            v.x = x.x + y.x; v.y = x.y + y.y; v.z = x.z + y.z; v.w = x.w + y.w;
        } else {
            const short* Ws = (const short*)W;
            short4v x = *(const short4v*)(Ws + r * 2048 + k);
            short4v y = *(const short4v*)(Ws + r * 2048 + 1024 + k);
            v.x = s2f(x.x) + s2f(y.x); v.y = s2f(x.y) + s2f(y.y);
            v.z = s2f(x.z) + s2f(y.z); v.w = s2f(x.w) + s2f(y.w);
        }
    } else {
        if (f) v = *(const float4*)((const float*)W + r * 1024 + k);
        else {
            short4v x = *(const short4v*)((const short*)W + r * 1024 + k);
            v.x = s2f(x.x); v.y = s2f(x.y); v.z = s2f(x.z); v.w = s2f(x.w);
        }
    }
    short4v o = { f2b(v.x), f2b(v.y), f2b(v.z), f2b(v.w) };
    *(short4v*)(wcat + i0) = o;
}

// u partial: 64 splits x 16 j each (R9 lesson: 64 serial iters was a 40 µs straggler)
template <int F>
DI void u_part(const void* fc3_w, const void* fca_w, float* __restrict__ uP, int jsplit) {
    int k4 = threadIdx.x * 4;
    float4 acc = {0.f, 0.f, 0.f, 0.f};
    for (int j = jsplit * 16; j < jsplit * 16 + 16; j++) {
        float fa = LD<F>(fca_w, j);
        float4 row;
        if (F) row = *(const float4*)((const float*)fc3_w + j * 1024 + k4);
        else {
            short4v x = *(const short4v*)((const short*)fc3_w + j * 1024 + k4);
            row.x = s2f(x.x); row.y = s2f(x.y); row.z = s2f(x.z); row.w = s2f(x.w);
        }
        acc.x += fa * row.x; acc.y += fa * row.y;
        acc.z += fa * row.z; acc.w += fa * row.w;
    }
    *(float4*)(uP + jsplit * 1024 + k4) = acc;
}

template <int F>
DI void c0_part(const void* fc3_b, const void* fca_w, const void* fca_b,
                float* c0, float* red) {
    float acc = 0.f;
    for (int j = threadIdx.x; j < 1024; j += 256)
        acc += LD<F>(fc3_b, j) * LD<F>(fca_w, j);
    red[threadIdx.x] = acc;
    __syncthreads();
    for (int s = 128; s > 0; s >>= 1) {
        if (threadIdx.x < s) red[threadIdx.x] += red[threadIdx.x + s];
        __syncthreads();
    }
    if (threadIdx.x == 0) *c0 = red[0] + LD<F>(fca_b, 0);
}

// SIMT GEMM for tiny fc2 (M=80,N=1024,K=300), k-split to [kb,ke), lds = 2176 floats
template <int F>
DI void fc2_part(float* lds, const void* word, const void* fc2_w, float* C,
                 int bx, int by, int kb, int ke) {
    float* As = lds;            // [16][68]
    float* Ws2 = lds + 1088;    // [16][68]
    const int tid = threadIdx.x;
    const int tx = tid & 15, ty = tid >> 4;
    const int m0 = by * 64, n0 = bx * 64;
    const int M = 80;
    float acc[4][4] = {};

    for (int k0 = kb; k0 < ke; k0 += 16) {
#pragma unroll
        for (int i = 0; i < 4; i++) {
            int idx = tid + i * 256;
            int kk = idx & 15, mm = idx >> 4;
            int m = m0 + mm, k = k0 + kk;
            As[kk * 68 + mm] = (m < M && k < ke) ? LD<F>(word, m * 300 + k) : 0.f;
        }
#pragma unroll
        for (int i = 0; i < 4; i++) {
            int idx = tid + i * 256;
            int kk = idx & 15, nn = idx >> 4;
            int n = n0 + nn, k = k0 + kk;
            Ws2[kk * 68 + nn] = (k < ke) ? LD<F>(fc2_w, n * 300 + k) : 0.f;
        }
        __syncthreads();
#pragma unroll
        for (int kk = 0; kk < 16; kk++) {
            float4 av = *(const float4*)(&As[kk * 68 + ty * 4]);
            float4 wv = *(const float4*)(&Ws2[kk * 68 + tx * 4]);
            float a4[4] = {av.x, av.y, av.z, av.w};
            float w4[4] = {wv.x, wv.y, wv.z, wv.w};
#pragma unroll
            for (int i = 0; i < 4; i++)
#pragma unroll
                for (int j = 0; j < 4; j++)
                    acc[i][j] += a4[i] * w4[j];
        }
        __syncthreads();
    }

    for (int i = 0; i < 4; i++) {
        int m = m0 + ty * 4 + i;
        if (m >= M) continue;
        for (int j = 0; j < 4; j++)
            C[m * 1024 + n0 + tx * 4 + j] = acc[i][j];
    }
}

// ONE dispatch for all independent prep; all sub-jobs now have short serial depth.
__global__ __launch_bounds__(256) void mega_prep(
    const int* flag,
    const void* fmap, const void* fc1_w, const void* u5w, const void* fco_w,
    const void* w3, const void* w4, const void* w5, const void* u3,
    const void* fc3_w, const void* fc3_b, const void* fca_w, const void* fca_b,
    const void* word, const void* fc2_w,
    short* fmap_b, short* fc1w_b, short* u5w_b, short* wcat_b, short* fcow_b,
    float* uP, float* c0, float* f_wdP) {
    __shared__ float lds[2176];
    int f = *flag;
    int bid = blockIdx.x;
    if (bid < 64) {
        if (f) u_part<1>(fc3_w, fca_w, uP, bid);
        else   u_part<0>(fc3_w, fca_w, uP, bid);
    } else if (bid == 64) {
        if (f) c0_part<1>(fc3_b, fca_w, fca_b, c0, lds);
        else   c0_part<0>(fc3_b, fca_w, fca_b, c0, lds);
    } else if (bid < 193) {
        int r = bid - 65;
        int sp = r >> 5, rr = r & 31;
        int kb = sp * 80, ke = (sp == 3) ? 300 : kb + 80;
        float* C = f_wdP + sp * 81920;
        if (f) fc2_part<1>(lds, word, fc2_w, C, rr & 15, rr >> 4, kb, ke);
        else   fc2_part<0>(lds, word, fc2_w, C, rr & 15, rr >> 4, kb, ke);
    }
    else if (bid < 977)  cvt_part(f, fmap,  fmap_b, bid - 193,  802816);
    else if (bid < 2001) cvt_part(f, fc1_w, fc1w_b, bid - 977,  1048576);
    else if (bid < 3025) cvt_part(f, u5w,   u5w_b,  bid - 2001, 1048576);
    else if (bid < 7121) wcat_part(f, w3, w4, w5, u3, wcat_b, bid - 3025);
    else                 cvt_part(f, fco_w, fcow_b, bid - 7121, 4194304);
}

// reduce uP[64][1024] -> u, f_wdP[4][81920] -> f_wd  (tiny, ~1.6 MB)
__global__ __launch_bounds__(256) void reduce_pre(
    const float* __restrict__ uP, const float* __restrict__ f_wdP,
    float* __restrict__ u, float* __restrict__ f_wd) {
    if (blockIdx.x < 80) {
        int i4 = (blockIdx.x * 256 + threadIdx.x) * 4;
        float4 a = *(const float4*)(f_wdP + i4);
        float4 b = *(const float4*)(f_wdP + 81920 + i4);
        float4 c = *(const float4*)(f_wdP + 163840 + i4);
        float4 d = *(const float4*)(f_wdP + 245760 + i4);
        float4 o = {a.x+b.x+c.x+d.x, a.y+b.y+c.y+d.y, a.z+b.z+c.z+d.z, a.w+b.w+c.w+d.w};
        *(float4*)(f_wd + i4) = o;
    } else {
        int k4 = threadIdx.x * 4;
        float4 acc = {0.f, 0.f, 0.f, 0.f};
        for (int p = 0; p < 64; p++) {
            float4 q = *(const float4*)(uP + p * 1024 + k4);
            acc.x += q.x; acc.y += q.y; acc.z += q.z; acc.w += q.w;
        }
        *(float4*)(u + k4) = acc;
    }
}

// ================= bf16 MFMA GEMM core — SOFTWARE-PIPELINED (R9 lesson) =================
// Prefetch next K-chunk into regs right after the first barrier so global-load
// latency overlaps MFMA + second barrier. Critical path/iter: LDS write + 2
// barriers + ds_read + 4 MFMA.
DI void mcore_b(const short* __restrict__ A, int lda,
                const short* __restrict__ B, int ldb,
                float* __restrict__ C, int ldc,
                int M, int kb, int ke, int m0, int n0) {
    __shared__ short As[4][64][8];
    __shared__ short Ws[4][64][8];
    const int tid = threadIdx.x;
    const int wv = tid >> 6, lane = tid & 63;
    const int mA = tid & 63, qA = tid >> 6;
    const int gm = m0 + mA;
    const int lp = (mA & 15) | (qA << 4), lg = mA >> 4;
    f32x4 acc[4] = {};

    s8v va = {0,0,0,0,0,0,0,0};
    if (gm < M) va = *(const s8v*)(A + gm * lda + kb + 8 * qA);
    s8v vb = *(const s8v*)(B + (n0 + mA) * ldb + kb + 8 * qA);

    for (int k0 = kb; k0 < ke; k0 += 32) {
        *(s8v*)&As[lg][lp][0] = va;
        *(s8v*)&Ws[lg][lp][0] = vb;
        __syncthreads();
        int kn = k0 + 32;
        if (kn < ke) {
            if (gm < M) va = *(const s8v*)(A + gm * lda + kn + 8 * qA);
            vb = *(const s8v*)(B + (n0 + mA) * ldb + kn + 8 * qA);
        }
        s8v af = *(const s8v*)&As[wv][lane][0];
#pragma unroll
        for (int nf = 0; nf < 4; nf++) {
            s8v bf = *(const s8v*)&Ws[nf][lane][0];
            acc[nf] = __builtin_amdgcn_mfma_f32_16x16x32_bf16(af, bf, acc[nf], 0, 0, 0);
        }
        __syncthreads();
    }

    const int q = lane >> 4, cc = lane & 15;
#pragma unroll
    for (int nf = 0; nf < 4; nf++) {
        int n = n0 + 16 * nf + cc;
#pragma unroll
        for (int r = 0; r < 4; r++) {
            int m = m0 + 16 * wv + q * 4 + r;
            if (m < M) C[m * ldc + n] = acc[nf][r];
        }
    }
}

__global__ __launch_bounds__(256) void mfma_fc1(
    const short* __restrict__ fmap_b, const short* __restrict__ fc1w_b,
    float* __restrict__ fhP) {
    int z = blockIdx.z;
    mcore_b(fmap_b, 1024, fc1w_b, 1024, fhP + z * 802816, 1024,
            NPIX, z * 512, z * 512 + 512, blockIdx.y * 64, blockIdx.x * 64);
}

__global__ __launch_bounds__(256) void mfma_gate(
    const short* __restrict__ a_b, const short* __restrict__ nodes_b,
    const short* __restrict__ wcat_b, float* __restrict__ gP) {
    int z = blockIdx.z;
    const short* A = (blockIdx.x >= 48) ? nodes_b : a_b;
    mcore_b(A, 1024, wcat_b, 1024, gP + z * 1310720, 4096,
            320, z * 512, z * 512 + 512, blockIdx.y * 64, blockIdx.x * 64);
}

// u5 GEMM with FUSED ew_upd epilogue, pipelined K-loop (K=1024, no split).
__global__ __launch_bounds__(256) void mfma_u5f(
    const int* flag, const short* __restrict__ rn_b, const short* __restrict__ u5w_b,
    const float* __restrict__ gP,
    const void* b3, const void* u3b, const void* b5, const void* u5b,
    float* __restrict__ nodes, short* __restrict__ nodes_b) {
    __shared__ short As[4][64][8];
    __shared__ short Ws[4][64][8];
    const int tid = threadIdx.x;
    const int wv = tid >> 6, lane = tid & 63;
    const int mA = tid & 63, qA = tid >> 6;
    const int lp = (mA & 15) | (qA << 4), lg = mA >> 4;
    const int m0 = blockIdx.y * 64, n0 = blockIdx.x * 64;
    f32x4 acc[4] = {};

    s8v va = *(const s8v*)(rn_b + (m0 + mA) * 1024 + 8 * qA);
    s8v vb = *(const s8v*)(u5w_b + (n0 + mA) * 1024 + 8 * qA);

    for (int k0 = 0; k0 < 1024; k0 += 32) {
        *(s8v*)&As[lg][lp][0] = va;
        *(s8v*)&Ws[lg][lp][0] = vb;
        __syncthreads();
        int kn = k0 + 32;
        if (kn < 1024) {
            va = *(const s8v*)(rn_b + (m0 + mA) * 1024 + kn + 8 * qA);
            vb = *(const s8v*)(u5w_b + (n0 + mA) * 1024 + kn + 8 * qA);
        }
        s8v af = *(const s8v*)&As[wv][lane][0];
#pragma unroll
        for (int nf = 0; nf < 4; nf++) {
            s8v bf = *(const s8v*)&Ws[nf][lane][0];
            acc[nf] = __builtin_amdgcn_mfma_f32_16x16x32_bf16(af, bf, acc[nf], 0, 0, 0);
        }
        __syncthreads();
    }

    const int f = *flag;
    const int q = lane >> 4, cc = lane & 15;
#pragma unroll
    for (int nf = 0; nf < 4; nf++) {
        int n = n0 + 16 * nf + cc;
        float bb3 = LDf(f, b3, n), bu3 = LDf(f, u3b, n);
        float bb5 = LDf(f, b5, n), bu5 = LDf(f, u5b, n);
#pragma unroll
        for (int r = 0; r < 4; r++) {
            int m = m0 + 16 * wv + q * 4 + r;
            int i = m * 1024 + n, base = m * 4096;
            float az = gP[base + n]        + gP[1310720 + base + n];
            float ah = gP[base + 2048 + n] + gP[1310720 + base + 2048 + n];
            float ux = gP[base + 3072 + n] + gP[1310720 + base + 3072 + n];
            float z = fast_sigmoid(az + ux + bb3 + bu3);
            float h = fast_tanh(ah + acc[nf][r] + bb5 + bu5);
            float nd = (1.f - z) * nodes[i] + z * h;
            nodes[i] = nd;
            nodes_b[i] = f2b(nd);
        }
    }
}

// final GEMM with FUSED bias+tanh+store, pipelined (K=2048, A switches at 1024).
__global__ __launch_bounds__(256) void mfma_finf(
    const int* flag, const short* __restrict__ nodes_b, const short* __restrict__ g_b,
    const short* __restrict__ fcow_b, const void* fco_b, void* out) {
    __shared__ short As[4][64][8];
    __shared__ short Ws[4][64][8];
    const int tid = threadIdx.x;
    const int wv = tid >> 6, lane = tid & 63;
    const int mA = tid & 63, qA = tid >> 6;
    const int lp = (mA & 15) | (qA << 4), lg = mA >> 4;
    const int m0 = blockIdx.y * 64, n0 = blockIdx.x * 64;
    f32x4 acc[4] = {};

    s8v va = *(const s8v*)(nodes_b + (m0 + mA) * 1024 + 8 * qA);
    s8v vb = *(const s8v*)(fcow_b + (n0 + mA) * 2048 + 8 * qA);

    for (int k0 = 0; k0 < 2048; k0 += 32) {
        *(s8v*)&As[lg][lp][0] = va;
        *(s8v*)&Ws[lg][lp][0] = vb;
        __syncthreads();
        int kn = k0 + 32;
        if (kn < 2048) {
            const short* Apn = (kn < 1024) ? nodes_b : (g_b - 1024);
            va = *(const s8v*)(Apn + (m0 + mA) * 1024 + kn + 8 * qA);
            vb = *(const s8v*)(fcow_b + (n0 + mA) * 2048 + kn + 8 * qA);
        }
        s8v af = *(const s8v*)&As[wv][lane][0];
#pragma unroll
        for (int nf = 0; nf < 4; nf++) {
            s8v bf = *(const s8v*)&Ws[nf][lane][0];
            acc[nf] = __builtin_amdgcn_mfma_f32_16x16x32_bf16(af, bf, acc[nf], 0, 0, 0);
        }
        __syncthreads();
    }

    const int f = *flag;
    const int q = lane >> 4, cc = lane & 15;
#pragma unroll
    for (int nf = 0; nf < 4; nf++) {
        int n = n0 + 16 * nf + cc;
        float bias = LDf(f, fco_b, n);
#pragma unroll
        for (int r = 0; r < 4; r++) {
            int m = m0 + 16 * wv + q * 4 + r;
            float v = fast_tanh(acc[nf][r] + bias);
            if (f) ((float*)out)[m * 2048 + n] = v;
            else   ((__hip_bfloat16*)out)[m * 2048 + n] = __float2bfloat16(v);
        }
    }
}

// ---------------- coeff: float4, final u ----------------
__global__ __launch_bounds__(256) void coeff_kernel(
    const float* __restrict__ fhP, const float* __restrict__ f_wd,
    const float* __restrict__ u, const float* __restrict__ c0p,
    float* __restrict__ s) {
    int n = blockIdx.x;  // 0..783
    __shared__ float4 fh4[256];
    __shared__ float4 uu4[256];
    int t = threadIdx.x;
    {
        float4 a0 = *(const float4*)(fhP + n * 1024 + t * 4);
        float4 a1 = *(const float4*)(fhP + 802816 + n * 1024 + t * 4);
        float4 fv = {a0.x + a1.x, a0.y + a1.y, a0.z + a1.z, a0.w + a1.w};
        fh4[t] = fv;
        uu4[t] = *(const float4*)(u + t * 4);
    }
    __syncthreads();
    float c0 = *c0p;
    int wave = t >> 6, lane = t & 63;
    int b = n / 196, hw = n % 196;
    int l0 = blockIdx.y * 40;
    for (int l = l0 + wave; l < l0 + 40; l += 4) {
        const float4* fd4 = (const float4*)(f_wd + l * 1024);
        float p = 0.f;
#pragma unroll
        for (int k = 0; k < 4; k++) {
            int idx = lane + k * 64;
            float4 h = fh4[idx];
            float4 d = fd4[idx];
            float4 uu = uu4[idx];
            p += fast_tanh(h.x * d.x) * uu.x;
            p += fast_tanh(h.y * d.y) * uu.y;
            p += fast_tanh(h.z * d.z) * uu.z;
            p += fast_tanh(h.w * d.w) * uu.w;
        }
        for (int off = 32; off > 0; off >>= 1) p += __shfl_down(p, off);
        if (lane == 0) s[b * PBATCH + hw * LL + l] = p + c0;
    }
}

// ---------------- softmax over contiguous 196-chunks ----------------
__global__ __launch_bounds__(64) void softmax196(float* __restrict__ s) {
    float* p = s + blockIdx.x * 196;
    int lane = threadIdx.x;
    float v[4];
    float mx = -1e30f;
#pragma unroll
    for (int i = 0; i < 4; i++) {
        int idx = lane + i * 64;
        v[i] = (idx < 196) ? p[idx] : -1e30f;
        mx = fmaxf(mx, v[i]);
    }
    for (int off = 32; off > 0; off >>= 1) mx = fmaxf(mx, __shfl_down(mx, off));
    mx = __shfl(mx, 0);
    float sum = 0.f;
#pragma unroll
    for (int i = 0; i < 4; i++) {
        int idx = lane + i * 64;
        if (idx < 196) { v[i] = __expf(v[i] - mx); sum += v[i]; }
    }
    for (int off = 32; off > 0; off >>= 1) sum += __shfl_down(sum, off);
    sum = __shfl(sum, 0);
    float inv = 1.f / sum;
#pragma unroll
    for (int i = 0; i < 4; i++) {
        int idx = lane + i * 64;
        if (idx < 196) p[idx] = v[i] * inv;
    }
}

// ---------------- g: reads bf16 fmap_b, 4 c per thread ----------------
__global__ __launch_bounds__(256) void g_kernel(
    const float* __restrict__ s, const short* __restrict__ fmap_b,
    float* __restrict__ nodes, short* __restrict__ nodes_b, short* __restrict__ g_b) {
    int bl = blockIdx.x;
    int b = bl / LL, l = bl % LL;
    __shared__ float co[196];
    for (int i = threadIdx.x; i < 196; i += 256)
        co[i] = s[b * PBATCH + i * LL + l];
    __syncthreads();
    int c4 = threadIdx.x * 4;
    const short* base = fmap_b + b * 196 * 1024 + c4;
    float a0 = 0.f, a1 = 0.f, a2 = 0.f, a3 = 0.f;
    for (int hw = 0; hw < 196; hw++) {
        short4v v = *(const short4v*)(base + hw * 1024);
        float w = co[hw];
        a0 += w * s2f(v.x); a1 += w * s2f(v.y);
        a2 += w * s2f(v.z); a3 += w * s2f(v.w);
    }
    int o = bl * 1024 + c4;
    float4 fa = {a0, a1, a2, a3};
    *(float4*)(nodes + o) = fa;
    short4v bb = { f2b(a0), f2b(a1), f2b(a2), f2b(a3) };
    *(short4v*)(nodes_b + o) = bb;
    *(short4v*)(g_b + o) = bb;
}

// ---------------- adj: 4 c per thread ----------------
template <int F>
DI void adj_core(float* arw, const void* adj, const float* nodes, short* a_b) {
    int bl = blockIdx.x;
    int b = bl / LL, l = bl % LL;
    if (threadIdx.x < LL) arw[threadIdx.x] = LD<F>(adj, l * LL + threadIdx.x);
    __syncthreads();
    int c4 = threadIdx.x * 4;
    const float* nb = nodes + b * LL * 1024 + c4;
    float a0 = 0.f, a1 = 0.f, a2 = 0.f, a3 = 0.f;
    for (int m = 0; m < LL; m++) {
        float am = arw[m];
        float4 nd = *(const float4*)(nb + m * 1024);
        a0 += am * nd.x; a1 += am * nd.y; a2 += am * nd.z; a3 += am * nd.w;
    }
    short4v bb = { f2b(a0), f2b(a1), f2b(a2), f2b(a3) };
    *(short4v*)(a_b + bl * 1024 + c4) = bb;
}

__global__ __launch_bounds__(256) void adj_kernel(
    const int* flag, const void* adj, const float* nodes, short* a_b) {
    __shared__ float arw[LL];
    if (*flag) adj_core<1>(arw, adj, nodes, a_b);
    else       adj_core<0>(arw, adj, nodes, a_b);
}

// ---------------- rn_b = bf16( sigmoid(ar + u3x + b4 + u3b) * nodes ), x4 ----------------
template <int F>
DI void ew_r_core(const float* gP, const float* nodes,
                  const void* b4, const void* u3b, short* rn_b, int i4) {
    int m = i4 >> 10, c = i4 & 1023;
    int base = m * 4096;
    float4 r0 = *(const float4*)(gP + base + 1024 + c);
    float4 r1 = *(const float4*)(gP + 1310720 + base + 1024 + c);
    float4 x0 = *(const float4*)(gP + base + 3072 + c);
    float4 x1 = *(const float4*)(gP + 1310720 + base + 3072 + c);
    float4 nd = *(const float4*)(nodes + i4);
    short4v o;
    o.x = f2b(fast_sigmoid(r0.x + r1.x + x0.x + x1.x + LD<F>(b4, c)   + LD<F>(u3b, c))   * nd.x);
    o.y = f2b(fast_sigmoid(r0.y + r1.y + x0.y + x1.y + LD<F>(b4, c+1) + LD<F>(u3b, c+1)) * nd.y);
    o.z = f2b(fast_sigmoid(r0.z + r1.z + x0.z + x1.z + LD<F>(b4, c+2) + LD<F>(u3b, c+2)) * nd.z);
    o.w = f2b(fast_sigmoid(r0.w + r1.w + x0.w + x1.w + LD<F>(b4, c+3) + LD<F>(u3b, c+3)) * nd.w);
    *(short4v*)(rn_b + i4) = o;
}

__global__ void ew_r(const int* flag, const float* gP, const float* nodes,
                     const void* b4, const void* u3b, short* rn_b, int n) {
    int i4 = (blockIdx.x * 256 + threadIdx.x) * 4;
    if (i4 >= n) return;
    if (*flag) ew_r_core<1>(gP, nodes, b4, u3b, rn_b, i4);
    else       ew_r_core<0>(gP, nodes, b4, u3b, rn_b, i4);
}

extern "C" void kernel_launch(void* const* d_in, const int* in_sizes, int n_in,
                              void* d_out, int out_size, void* d_ws, size_t ws_size,
                              hipStream_t stream) {
    const void* fmap  = d_in[0];
    const void* word  = d_in[1];
    const void* adjm  = d_in[2];
    const void* fc1_w = d_in[3];
    const void* fc2_w = d_in[4];
    const void* fc3_w = d_in[5];
    const void* fc3_b = d_in[6];
    const void* fca_w = d_in[7];
    const void* fca_b = d_in[8];
    const void* w3    = d_in[9];
    const void* b3    = d_in[10];
    const void* u3    = d_in[11];
    const void* u3b   = d_in[12];
    const void* w4    = d_in[13];
    const void* b4    = d_in[14];
    const void* w5    = d_in[15];
    const void* b5    = d_in[16];
    const void* u5    = d_in[17];
    const void* u5b   = d_in[18];
    const void* fco_w = d_in[19];
    const void* fco_b = d_in[20];

    // ---- workspace: increments in FLOATS (bf16 buffers = elems/2). ~35 MB.
    int*   flag    = (int*)d_ws;
    float* P       = (float*)d_ws + 16;
    float* nodes   = P;                       P += 327680;   // f32, persistent
    short* nodes_b = (short*)P;               P += 163840;   // 327680 bf16
    short* g_b     = (short*)P;               P += 163840;   // 327680 bf16
    short* a_b     = (short*)P;               P += 163840;   // 327680 bf16
    short* rn_b    = (short*)P;               P += 163840;   // 327680 bf16
    short* u5w_b   = (short*)P;               P += 524288;   // 1048576 bf16
    short* wcat_b  = (short*)P;               P += 2097152;  // 4194304 bf16
    float* R       = P;                                      // overlay region
    // semantic phase (3,070,224 f)
    float* fhP    = R;                            // 2 x 802816
    float* f_wd   = R + 1605632;                  // 81920
    float* f_wdP  = f_wd + 81920;                 // 4 x 81920
    float* uP     = f_wdP + 327680;               // 64 x 1024 partials
    float* u      = uP + 65536;                   // 1024
    float* c0     = u + 1024;                     // 16
    float* s      = c0 + 16;                      // 62720
    short* fmap_b = (short*)(s + 62720);          // 802816 shorts = 401408 f
    short* fc1w_b = (short*)(s + 62720 + 401408); // 1048576 shorts = 524288 f
    // fco weight copy: past semantic tail, disjoint from gP (GGNN: 2,621,440 f)
    short* fcow_b = (short*)(R + 3070224);        // 4194304 shorts = 2097152 f
    // GGNN phase overlays semantic scratch only
    float* gP     = R;                            // 2 x 1310720

    // ---- dtype detection ----
    detect_dtype<<<1, 256, 0, stream>>>(fc1_w, 4096, flag);

    // ---- all independent prep in ONE dispatch ----
    mega_prep<<<11217, 256, 0, stream>>>(flag, fmap, fc1_w, u5, fco_w,
                                         w3, w4, w5, u3,
                                         fc3_w, fc3_b, fca_w, fca_b,
                                         word, fc2_w,
                                         fmap_b, fc1w_b, u5w_b, wcat_b, fcow_b,
                                         uP, c0, f_wdP);
    reduce_pre<<<81, 256, 0, stream>>>(uP, f_wdP, u, f_wd);

    // ---- semantic stage ----
    mfma_fc1<<<dim3(16, 13, 2), 256, 0, stream>>>(fmap_b, fc1w_b, fhP);
    coeff_kernel<<<dim3(NPIX, 2), 256, 0, stream>>>(fhP, f_wd, u, c0, s);
    softmax196<<<320, 64, 0, stream>>>(s);
    g_kernel<<<320, 256, 0, stream>>>(s, fmap_b, nodes, nodes_b, g_b);

    // ---- GGNN: 3 time steps (u5 GEMM has fused ew_upd epilogue) ----
    for (int t = 0; t < 3; t++) {
        adj_kernel<<<320, 256, 0, stream>>>(flag, adjm, nodes, a_b);
        mfma_gate<<<dim3(64, 5, 2), 256, 0, stream>>>(a_b, nodes_b, wcat_b, gP);
        ew_r<<<320, 256, 0, stream>>>(flag, gP, nodes, b4, u3b, rn_b, 327680);
        mfma_u5f<<<dim3(16, 5), 256, 0, stream>>>(flag, rn_b, u5w_b, gP,
                                                  b3, u3b, b5, u5b, nodes, nodes_b);
    }

    // ---- output: tanh([nodes|g] @ fco_w.T + fco_b), fused epilogue ----
    mfma_finf<<<dim3(32, 5), 256, 0, stream>>>(flag, nodes_b, g_b, fcow_b, fco_b, d_out);
}